// Round 1
// baseline (107.423 us; speedup 1.0000x reference)
//
#include <hip/hip_runtime.h>
#include <math.h>

// Spherical voxelization: points [B,N,3] f32 -> hist [B,1,5,30,15] f32
// B=16, N=65536, bins = 5*30*15 = 2250.

constexpr int RAD_N = 5, AZI_N = 30, ELE_N = 15;
constexpr int BINS  = RAD_N * AZI_N * ELE_N;   // 2250
constexpr int BLOCK = 256;
constexpr int PPB   = 2048;                    // points per block (8 per thread)

__global__ __launch_bounds__(BLOCK) void voxel_kernel(
    const float* __restrict__ pts, float* __restrict__ out,
    int N, int blocksPerBatch)
{
    __shared__ float hist[BINS];
    for (int j = threadIdx.x; j < BINS; j += BLOCK) hist[j] = 0.0f;
    __syncthreads();

    const int batch = blockIdx.x / blocksPerBatch;
    const int bib   = blockIdx.x % blocksPerBatch;
    const int base  = bib * PPB;

    // Constants: computed in double (as Python does), cast to f32 (JAX weak-type promotion).
    const float TWO_PI_F   = (float)(6.283185307179586);
    const float PI_F       = (float)(3.141592653589793);
    const float tr         = (float)(2.0 / 5.0);           // 0.4
    const float sr         = (float)(2.0 / 5.0 / 2.0);     // 0.2
    const float tr_p_sr    = (float)(0.4 + 0.2);           // 0.6
    const float rhi_lo     = (float)(2.0 - 0.2);           // 1.8
    const float DES_R_F    = 2.0f;
    const float ta         = (float)(6.283185307179586 / 30.0);
    const float te         = (float)(3.141592653589793 / 15.0);
    const float se         = (float)(3.141592653589793 / 30.0);
    const float te_p_se    = (float)(3.141592653589793 / 15.0 + 3.141592653589793 / 30.0);
    const float te075      = (float)(0.75 * (3.141592653589793 / 15.0));
    const float pi_m_se    = (float)(3.141592653589793 - 3.141592653589793 / 30.0);

    const size_t batch_off = (size_t)batch * N;

    for (int k = 0; k < PPB / BLOCK; ++k) {
        int i = base + k * BLOCK + threadIdx.x;
        if (i >= N) continue;
        size_t pidx = (batch_off + i) * 3;
        float x = pts[pidx + 0];
        float y = pts[pidx + 1];
        float z = pts[pidx + 2];

        float r = sqrtf(x * x + y * y + z * z);
        float azi = atan2f(y, x);
        if (azi < 0.0f) azi += TWO_PI_F;
        float cz = z / fmaxf(r, 1e-12f);
        cz = fminf(fmaxf(cz, -1.0f), 1.0f);
        float ele = acosf(cz);

        // ---- radial axis ----
        bool lowR  = r < sr;
        bool highR = (r > rhi_lo) && (r <= DES_R_F);
        float rd1 = 1e30f, rd2 = 1e30f; int ri1 = 0, ri2 = 0;
#pragma unroll
        for (int j = 0; j < RAD_N; ++j) {
            float c = ((float)j + 0.5f) * tr;
            float d = fabsf(r - c);
            if (lowR) {
                if (d <= sr) d = 0.0f;
                else if (d > tr && d <= tr_p_sr) d = tr;
            }
            if (highR) {
                if (d > tr && d <= tr_p_sr) d = tr;
            }
            if (d < rd1) { rd2 = rd1; ri2 = ri1; rd1 = d; ri1 = j; }
            else if (d < rd2) { rd2 = d; ri2 = j; }
        }
        float wr1 = 1.0f + (-rd1) / tr;
        float wr2 = 1.0f + (-rd2) / tr;
        if (r > DES_R_F) { wr1 = 0.0f; wr2 = 0.0f; }

        // ---- azimuth axis (circular) ----
        float ad1 = 1e30f, ad2 = 1e30f; int ai1 = 0, ai2 = 0;
#pragma unroll
        for (int j = 0; j < AZI_N; ++j) {
            float c = ((float)j + 0.5f) * ta;
            float d = fabsf(azi - c);
            d = fminf(d, TWO_PI_F - d);
            if (d < ad1) { ad2 = ad1; ai2 = ai1; ad1 = d; ai1 = j; }
            else if (d < ad2) { ad2 = d; ai2 = j; }
        }
        float wa1 = 1.0f + (-ad1) / ta;
        float wa2 = 1.0f + (-ad2) / ta;

        // ---- elevation axis ----
        bool lowE  = ele < se;
        bool highE = (ele > pi_m_se) && (ele <= PI_F);
        float ed1 = 1e30f, ed2 = 1e30f; int ei1 = 0, ei2 = 0;
#pragma unroll
        for (int j = 0; j < ELE_N; ++j) {
            float c = ((float)j + 0.5f) * te;
            float d = fabsf(ele - c);
            if (lowE) {
                if (d <= se) d = 0.0f;
                else if (d > te && d <= te_p_se) d = te;
            }
            if (highE) {
                if (d <= te075) d = 0.0f;
                else if (d > te && d <= te_p_se) d = te;
            }
            if (d < ed1) { ed2 = ed1; ei2 = ei1; ed1 = d; ei1 = j; }
            else if (d < ed2) { ed2 = d; ei2 = j; }
        }
        float we1 = 1.0f + (-ed1) / te;
        float we2 = 1.0f + (-ed2) / te;

        // ---- 8 trilinear scatter-adds into LDS histogram ----
        int   ri[2] = { ri1, ri2 };  float wr[2] = { wr1, wr2 };
        int   ai[2] = { ai1, ai2 };  float wa[2] = { wa1, wa2 };
        int   ei[2] = { ei1, ei2 };  float we[2] = { we1, we2 };
#pragma unroll
        for (int a = 0; a < 2; ++a) {
#pragma unroll
            for (int b = 0; b < 2; ++b) {
                float wra = wr[a] * wa[b];
#pragma unroll
                for (int c = 0; c < 2; ++c) {
                    float w = wra * we[c];
                    int idx = (ri[a] * AZI_N + ai[b]) * ELE_N + ei[c];
                    atomicAdd(&hist[idx], w);
                }
            }
        }
    }

    __syncthreads();
    float* ob = out + (size_t)batch * BINS;
    for (int j = threadIdx.x; j < BINS; j += BLOCK) {
        float v = hist[j];
        if (v != 0.0f) atomicAdd(&ob[j], v);
    }
}

extern "C" void kernel_launch(void* const* d_in, const int* in_sizes, int n_in,
                              void* d_out, int out_size, void* d_ws, size_t ws_size,
                              hipStream_t stream) {
    const float* pts = (const float*)d_in[0];
    float* out = (float*)d_out;

    const int B = 16;
    int total = in_sizes[0] / 3;       // B*N
    int N = total / B;                 // 65536
    int blocksPerBatch = (N + PPB - 1) / PPB;  // 32

    hipMemsetAsync(d_out, 0, (size_t)out_size * sizeof(float), stream);
    voxel_kernel<<<dim3(B * blocksPerBatch), dim3(BLOCK), 0, stream>>>(pts, out, N, blocksPerBatch);
}

// Round 2
// 95.408 us; speedup vs baseline: 1.1259x; 1.1259x over previous
//
#include <hip/hip_runtime.h>
#include <math.h>

// Spherical voxelization: points [B,N,3] f32 -> hist [B,1,5,30,15] f32
// B=16, N=65536, bins = 5*30*15 = 2250.
// Direct two-nearest-bin computation (uniform grids) instead of argmin loops.

constexpr int RAD_N = 5, AZI_N = 30, ELE_N = 15;
constexpr int BINS  = RAD_N * AZI_N * ELE_N;   // 2250
constexpr int BLOCK = 256;
constexpr int PPB   = 1024;                    // points per block (4 per thread)

__global__ __launch_bounds__(BLOCK) void voxel_kernel(
    const float* __restrict__ pts, float* __restrict__ out,
    int N, int blocksPerBatch)
{
    __shared__ float hist[BINS];
    for (int j = threadIdx.x; j < BINS; j += BLOCK) hist[j] = 0.0f;
    __syncthreads();

    const int batch = blockIdx.x / blocksPerBatch;
    const int bib   = blockIdx.x % blocksPerBatch;
    const int base  = bib * PPB;

    // f32 constants (double-rounded-to-f32, matching JAX weak-type promotion)
    const float TWO_PI_F = (float)(6.283185307179586);
    const float PI_F     = (float)(3.141592653589793);
    const float tr       = (float)(2.0 / 5.0);                 // 0.4
    const float sr       = (float)(2.0 / 5.0 / 2.0);           // 0.2
    const float tr_p_sr  = (float)(0.4 + 0.2);                 // 0.6
    const float rhi_lo   = (float)(2.0 - 0.2);                 // 1.8
    const float DES_R_F  = 2.0f;
    const float ta       = (float)(6.283185307179586 / 30.0);
    const float te       = (float)(3.141592653589793 / 15.0);
    const float se       = (float)(3.141592653589793 / 30.0);
    const float te_p_se  = (float)(3.141592653589793 / 15.0 + 3.141592653589793 / 30.0);
    const float te075    = (float)(0.75 * (3.141592653589793 / 15.0));
    const float pi_m_se  = (float)(3.141592653589793 - 3.141592653589793 / 30.0);

    const float inv_tr = (float)(5.0 / 2.0);
    const float inv_ta = (float)(30.0 / 6.283185307179586);
    const float inv_te = (float)(15.0 / 3.141592653589793);

    const size_t batch_off = (size_t)batch * N;

    for (int k = 0; k < PPB / BLOCK; ++k) {
        int i = base + k * BLOCK + threadIdx.x;
        if (i >= N) continue;
        size_t pidx = (batch_off + i) * 3;
        float x = pts[pidx + 0];
        float y = pts[pidx + 1];
        float z = pts[pidx + 2];

        float r = sqrtf(x * x + y * y + z * z);
        if (r > DES_R_F) continue;   // all 8 weights exactly 0 in reference

        float azi = atan2f(y, x);
        if (azi < 0.0f) azi += TWO_PI_F;
        float cz = z / fmaxf(r, 1e-12f);
        cz = fminf(fmaxf(cz, -1.0f), 1.0f);
        float ele = acosf(cz);

        // ---- radial: two nearest bins directly ----
        int ra = (int)(r * inv_tr);
        if (ra > RAD_N - 1) ra = RAD_N - 1;
        float cra = ((float)ra + 0.5f) * tr;
        int rb = (r > cra) ? ra + 1 : ra - 1;
        if (rb < 0) rb = 1;
        else if (rb > RAD_N - 1) rb = RAD_N - 2;
        float dra = fabsf(r - cra);
        float drb = fabsf(r - ((float)rb + 0.5f) * tr);
        {
            bool lowR  = r < sr;
            bool highR = (r > rhi_lo);   // r <= 2 guaranteed here
            if (lowR) {
                dra = (dra <= sr) ? 0.0f : ((dra > tr && dra <= tr_p_sr) ? tr : dra);
                drb = (drb <= sr) ? 0.0f : ((drb > tr && drb <= tr_p_sr) ? tr : drb);
            }
            if (highR) {
                if (dra > tr && dra <= tr_p_sr) dra = tr;
                if (drb > tr && drb <= tr_p_sr) drb = tr;
            }
        }
        float wra = 1.0f - dra * inv_tr;
        float wrb = 1.0f - drb * inv_tr;

        // ---- azimuth: circular, two nearest ----
        int aa = (int)(azi * inv_ta);
        if (aa > AZI_N - 1) aa = AZI_N - 1;
        float caa = ((float)aa + 0.5f) * ta;
        int ab = (azi > caa) ? aa + 1 : aa - 1;
        if (ab < 0) ab = AZI_N - 1;
        else if (ab > AZI_N - 1) ab = 0;
        float daa = fabsf(azi - caa);
        daa = fminf(daa, TWO_PI_F - daa);
        float dab = fabsf(azi - ((float)ab + 0.5f) * ta);
        dab = fminf(dab, TWO_PI_F - dab);
        float waa = 1.0f - daa * inv_ta;
        float wab = 1.0f - dab * inv_ta;

        // ---- elevation: two nearest ----
        int ea = (int)(ele * inv_te);
        if (ea > ELE_N - 1) ea = ELE_N - 1;
        float cea = ((float)ea + 0.5f) * te;
        int eb = (ele > cea) ? ea + 1 : ea - 1;
        if (eb < 0) eb = 1;
        else if (eb > ELE_N - 1) eb = ELE_N - 2;
        float dea = fabsf(ele - cea);
        float deb = fabsf(ele - ((float)eb + 0.5f) * te);
        {
            bool lowE  = ele < se;
            bool highE = (ele > pi_m_se) && (ele <= PI_F);
            if (lowE) {
                dea = (dea <= se) ? 0.0f : ((dea > te && dea <= te_p_se) ? te : dea);
                deb = (deb <= se) ? 0.0f : ((deb > te && deb <= te_p_se) ? te : deb);
            }
            if (highE) {
                dea = (dea <= te075) ? 0.0f : ((dea > te && dea <= te_p_se) ? te : dea);
                deb = (deb <= te075) ? 0.0f : ((deb > te && deb <= te_p_se) ? te : deb);
            }
        }
        float wea = 1.0f - dea * inv_te;
        float web = 1.0f - deb * inv_te;

        // ---- 8 trilinear scatter-adds into LDS histogram ----
        int rbase_a = ra * (AZI_N * ELE_N), rbase_b = rb * (AZI_N * ELE_N);
        int abase_a = aa * ELE_N,           abase_b = ab * ELE_N;
        float w_aa = wra * waa, w_ab = wra * wab;
        float w_ba = wrb * waa, w_bb = wrb * wab;
        atomicAdd(&hist[rbase_a + abase_a + ea], w_aa * wea);
        atomicAdd(&hist[rbase_a + abase_a + eb], w_aa * web);
        atomicAdd(&hist[rbase_a + abase_b + ea], w_ab * wea);
        atomicAdd(&hist[rbase_a + abase_b + eb], w_ab * web);
        atomicAdd(&hist[rbase_b + abase_a + ea], w_ba * wea);
        atomicAdd(&hist[rbase_b + abase_a + eb], w_ba * web);
        atomicAdd(&hist[rbase_b + abase_b + ea], w_bb * wea);
        atomicAdd(&hist[rbase_b + abase_b + eb], w_bb * web);
    }

    __syncthreads();
    float* ob = out + (size_t)batch * BINS;
    for (int j = threadIdx.x; j < BINS; j += BLOCK) {
        float v = hist[j];
        if (v != 0.0f) atomicAdd(&ob[j], v);
    }
}

extern "C" void kernel_launch(void* const* d_in, const int* in_sizes, int n_in,
                              void* d_out, int out_size, void* d_ws, size_t ws_size,
                              hipStream_t stream) {
    const float* pts = (const float*)d_in[0];
    float* out = (float*)d_out;

    const int B = 16;
    int total = in_sizes[0] / 3;                // B*N
    int N = total / B;                          // 65536
    int blocksPerBatch = (N + PPB - 1) / PPB;   // 64

    hipMemsetAsync(d_out, 0, (size_t)out_size * sizeof(float), stream);
    voxel_kernel<<<dim3(B * blocksPerBatch), dim3(BLOCK), 0, stream>>>(pts, out, N, blocksPerBatch);
}